// Round 1
// baseline (695.312 us; speedup 1.0000x reference)
//
#include <hip/hip_runtime.h>

// EdgeWeightNorm (norm='both'), EPS = 0.
// inputs: d_in[0]=edge_weight f32[E], d_in[1]=src i32[E], d_in[2]=dst i32[E],
//         d_in[3]=num_nodes scalar (fixed 100000 per setup_inputs).
// out: f32[E].
// d_ws layout: [0, N) outdeg f32, [N, 2N) indeg f32.

#define N_NODES 100000

__global__ void zero_ws(float* __restrict__ p, int n) {
    int i = blockIdx.x * blockDim.x + threadIdx.x;
    int stride = gridDim.x * blockDim.x;
    for (; i < n; i += stride) p[i] = 0.0f;
}

__global__ void degree_kernel(const float* __restrict__ w,
                              const int* __restrict__ src,
                              const int* __restrict__ dst,
                              float* __restrict__ outdeg,
                              float* __restrict__ indeg,
                              int n_edges) {
    int i = blockIdx.x * blockDim.x + threadIdx.x;
    int stride = gridDim.x * blockDim.x;
    for (; i < n_edges; i += stride) {
        float wi = w[i];
        atomicAdd(&outdeg[src[i]], wi);
        atomicAdd(&indeg[dst[i]], wi);
    }
}

__global__ void rsqrt_kernel(float* __restrict__ p, int n) {
    int i = blockIdx.x * blockDim.x + threadIdx.x;
    int stride = gridDim.x * blockDim.x;
    for (; i < n; i += stride) {
        // deg==0 -> inf, matches reference 0**-0.5
        p[i] = 1.0f / sqrtf(p[i]);
    }
}

__global__ void gather_kernel(const float* __restrict__ w,
                              const int* __restrict__ src,
                              const int* __restrict__ dst,
                              const float* __restrict__ srcn,
                              const float* __restrict__ dstn,
                              float* __restrict__ out,
                              int n_edges) {
    int i = blockIdx.x * blockDim.x + threadIdx.x;
    int stride = gridDim.x * blockDim.x;
    for (; i < n_edges; i += stride) {
        out[i] = srcn[src[i]] * dstn[dst[i]] * w[i];
    }
}

extern "C" void kernel_launch(void* const* d_in, const int* in_sizes, int n_in,
                              void* d_out, int out_size, void* d_ws, size_t ws_size,
                              hipStream_t stream) {
    const float* w   = (const float*)d_in[0];
    const int*   src = (const int*)d_in[1];
    const int*   dst = (const int*)d_in[2];
    const int n_edges = in_sizes[0];

    float* outdeg = (float*)d_ws;
    float* indeg  = outdeg + N_NODES;
    float* out    = (float*)d_out;

    const int block = 256;

    // 1) zero the degree accumulators (d_ws is poisoned, and we must be
    //    idempotent across replays)
    {
        int n = 2 * N_NODES;
        int grid = (n + block - 1) / block;
        zero_ws<<<grid, block, 0, stream>>>(outdeg, n);
    }

    // 2) weighted degree via atomics
    {
        int grid = 2048;
        degree_kernel<<<grid, block, 0, stream>>>(w, src, dst, outdeg, indeg, n_edges);
    }

    // 3) deg -> deg^-0.5 in place
    {
        int n = 2 * N_NODES;
        int grid = (n + block - 1) / block;
        rsqrt_kernel<<<grid, block, 0, stream>>>(outdeg, n);
    }

    // 4) per-edge product
    {
        int grid = 4096;
        gather_kernel<<<grid, block, 0, stream>>>(w, src, dst, outdeg, indeg, out, n_edges);
    }
}